// Round 6
// baseline (600.565 us; speedup 1.0000x reference)
//
#include <hip/hip_runtime.h>

typedef float  f32x4  __attribute__((ext_vector_type(4)));
typedef __bf16 bf16x8 __attribute__((ext_vector_type(8)));
typedef __bf16 bf16x4 __attribute__((ext_vector_type(4)));

#define DEVFN static __device__ __forceinline__

constexpr int BB = 2, SS = 4096, DD = 1024;
constexpr int MROWS = BB * SS; // 8192

// ---------------- workspace layout (bytes) ----------------
constexpr size_t SZ_QK   = (size_t)MROWS * DD * 2;
constexpr size_t SZ_VT   = (size_t)BB * DD * SS * 2;
constexpr size_t SZ_ATTN = (size_t)BB * SS * SS * 2;
constexpr size_t SZ_S    = (size_t)BB * SS * SS * 4;
constexpr size_t SZ_W    = (size_t)DD * DD * 2;

constexpr size_t O_VT   = 0;
constexpr size_t O_ATTN = O_VT + SZ_VT;
constexpr size_t O_QH   = O_ATTN;
constexpr size_t O_QL   = O_QH + SZ_QK;
constexpr size_t O_KH   = O_QL + SZ_QK;
constexpr size_t O_KL   = O_KH + SZ_QK;
constexpr size_t O_S    = O_ATTN + SZ_ATTN;
constexpr size_t O_XH   = O_S;
constexpr size_t O_XL   = O_XH + SZ_QK;
constexpr size_t O_WQH  = O_XL + SZ_QK;
constexpr size_t O_WQL  = O_WQH + SZ_W;
constexpr size_t O_WKH  = O_WQL + SZ_W;
constexpr size_t O_WKL  = O_WKH + SZ_W;
constexpr size_t O_WVH  = O_WKL + SZ_W;
constexpr size_t O_WVL  = O_WVH + SZ_W;
constexpr size_t WS_NEEDED = SZ_VT + SZ_ATTN + SZ_S;

// ---------------- helpers ----------------
DEVFN f32x4 mfma16x16x32(bf16x8 a, bf16x8 b, f32x4 c) {
  return __builtin_amdgcn_mfma_f32_16x16x32_bf16(a, b, c, 0, 0, 0);
}

DEVFN void gld16(const __bf16* g, char* l) {
  __builtin_amdgcn_global_load_lds((const __attribute__((address_space(1))) void*)g,
                                   (__attribute__((address_space(3))) void*)l, 16, 0, 0);
}

// bijective XCD-chunked block swizzle (requires total blocks % 8 == 0)
DEVFN void swz_xy(int& bx, int& by, int& bz) {
  const int gx = gridDim.x, gy = gridDim.y, gz = gridDim.z;
  const int lin = (blockIdx.z * gy + blockIdx.y) * gx + blockIdx.x;
  const int chunk = (gx * gy * gz) >> 3;
  const int nl = (lin & 7) * chunk + (lin >> 3);
  bx = nl % gx; const int r = nl / gx; by = r % gy; bz = r / gy;
}

// =====================================================================
// 256x256 GEMM core v5: 2 phases per K-tile, ONE barrier per phase.
//   ph0: ds_read a0(m0-3)+b(n0-3) [16 b128]; stage tile t+1 [8 gld]
//        into dead buffer; lgkm(0); 32 MFMA (m0-3 x n0-3); barrier.
//   ph1: ds_read a1(m4-7) [8]; lgkm(0); 32 MFMA (m4-7); vmcnt(0); barrier.
// Safety: reads drain at each phase's lgkm(0) before its end-barrier, so
// ph0(t)'s DMA into buf[(t+1)&1] (last read ph1(t-1)) cannot race; staged
// data forced by vmcnt(0) at ph1-end (issue->use ~2500 cyc > HBM 900).
// =====================================================================
struct Segs { const __bf16 *a0, *a1, *a2, *b0, *b1, *b2; };

DEVFN void gemm256_core(Segs s, int NT, char* smem, f32x4 (&acc)[8][4]) {
  const int tid = threadIdx.x, lane = tid & 63, wave = tid >> 6;
  const int wm = wave >> 2, wn = wave & 3;
  // staging: per-lane inverse-swizzled global source offset
  const size_t rk = (size_t)((wave << 3) + (lane >> 3)) * DD +
                    (size_t)((((lane & 7) ^ (lane >> 3)) << 3));
  const int wvoff = wave << 10;
  // fragment-read addressing (swizzled)
  const int rbA = (((wm << 7) + (lane & 15)) << 7);
  const int rbB = (((wn << 6) + (lane & 15)) << 7);
  const int cx0 = (((lane >> 4) << 4)) ^ ((lane & 7) << 4);
  const int cx1 = cx0 ^ 64;

  char* const LAb[2] = { smem,         smem + 65536 };
  char* const LBb[2] = { smem + 32768, smem + 98304 };

  auto stA = [&](int u, int q, char* dst) {
    int uc = (u < NT) ? u : (NT - 1);
    int sg = uc >> 4;
    const __bf16* p = (sg == 0) ? s.a0 : ((sg == 1) ? s.a1 : s.a2);
    gld16(p + ((size_t)(q << 6)) * DD + ((uc & 15) << 6) + rk, dst + (q << 13) + wvoff);
  };
  auto stB = [&](int u, int q, char* dst) {
    int uc = (u < NT) ? u : (NT - 1);
    int sg = uc >> 4;
    const __bf16* p = (sg == 0) ? s.b0 : ((sg == 1) ? s.b1 : s.b2);
    gld16(p + ((size_t)(q << 6)) * DD + ((uc & 15) << 6) + rk, dst + (q << 13) + wvoff);
  };
  auto rdA = [&](char* l, int m, int cx) { return *(const bf16x8*)(l + rbA + (m << 11) + cx); };
  auto rdB = [&](char* l, int n, int cx) { return *(const bf16x8*)(l + rbB + (n << 11) + cx); };

  // ---- prologue: stage tile 0 into buf0 ----
#pragma unroll
  for (int q = 0; q < 4; ++q) { stA(0, q, LAb[0]); stB(0, q, LBb[0]); }
  asm volatile("s_waitcnt vmcnt(0)" ::: "memory");
  __builtin_amdgcn_s_barrier();

  for (int t = 0; t < NT; ++t) {
    char* lA = LAb[t & 1];
    char* lB = LBb[t & 1];
    char* nA = LAb[(t + 1) & 1];
    char* nB = LBb[(t + 1) & 1];
    bf16x8 a[4][2], b[4][2];

    // ---- phase 0: a0 x (b0..b3) ----
#pragma unroll
    for (int m = 0; m < 4; ++m) { a[m][0] = rdA(lA, m, cx0); a[m][1] = rdA(lA, m, cx1); }
#pragma unroll
    for (int n = 0; n < 4; ++n) { b[n][0] = rdB(lB, n, cx0); b[n][1] = rdB(lB, n, cx1); }
#pragma unroll
    for (int q = 0; q < 4; ++q) { stA(t + 1, q, nA); stB(t + 1, q, nB); }
    asm volatile("s_waitcnt lgkmcnt(0)" ::: "memory");
    __builtin_amdgcn_sched_barrier(0);
    __builtin_amdgcn_s_setprio(1);
#pragma unroll
    for (int cx = 0; cx < 2; ++cx)
#pragma unroll
      for (int m = 0; m < 4; ++m)
#pragma unroll
        for (int n = 0; n < 4; ++n)
          acc[m][n] = mfma16x16x32(a[m][cx], b[n][cx], acc[m][n]);
    __builtin_amdgcn_s_setprio(0);
    __builtin_amdgcn_s_barrier();

    // ---- phase 1: a1 x (b0..b3) ----
#pragma unroll
    for (int m = 0; m < 4; ++m) { a[m][0] = rdA(lA, m + 4, cx0); a[m][1] = rdA(lA, m + 4, cx1); }
    asm volatile("s_waitcnt lgkmcnt(0)" ::: "memory");
    __builtin_amdgcn_sched_barrier(0);
    __builtin_amdgcn_s_setprio(1);
#pragma unroll
    for (int cx = 0; cx < 2; ++cx)
#pragma unroll
      for (int m = 0; m < 4; ++m)
#pragma unroll
        for (int n = 0; n < 4; ++n)
          acc[m + 4][n] = mfma16x16x32(a[m][cx], b[n][cx], acc[m + 4][n]);
    __builtin_amdgcn_s_setprio(0);
    asm volatile("s_waitcnt vmcnt(0)" ::: "memory"); // next tile fully landed
    __builtin_amdgcn_s_barrier();
  }
}

// =====================================================================
// 256x128 8-phase GEMM core (R5, unchanged — delivered well for PV/Vt)
// =====================================================================
DEVFN void gemm128_core(const __bf16* Ap, const __bf16* Bp, size_t ld, int NT,
                        char* smem, f32x4 (&acc)[4][4]) {
  const int tid = threadIdx.x, lane = tid & 63, wave = tid >> 6;
  const int wm = wave >> 1, wn = wave & 1;
  const size_t rk = (size_t)(tid >> 3) * ld +
                    (size_t)((((lane & 7) ^ (lane >> 3)) << 3));
  const int wvoff = wave << 10;
  const int rbA = (((wm << 6) + (lane & 15)) << 7);
  const int rbB = (((wn << 6) + (lane & 15)) << 7);
  const int cx0 = (((lane >> 4) << 4)) ^ ((lane & 7) << 4);
  const int cx1 = cx0 ^ 64;

  char* LA0 = smem;            // 32KB
  char* LB0 = smem + 32768;    // 16KB
  char* LA1 = smem + 49152;    // 32KB
  char* LB1 = smem + 81920;    // 16KB

  auto stA = [&](int u, int q, char* dst) {
    int uc = (u < NT) ? u : (NT - 1);
    gld16(Ap + (size_t)(q << 6) * ld + ((size_t)uc << 6) + rk, dst + (q << 13) + wvoff);
  };
  auto stB = [&](int u, int q, char* dst) {
    int uc = (u < NT) ? u : (NT - 1);
    gld16(Bp + (size_t)(q << 6) * ld + ((size_t)uc << 6) + rk, dst + (q << 13) + wvoff);
  };
  auto rdA = [&](char* l, int m, int cx) { return *(const bf16x8*)(l + rbA + (m << 11) + cx); };
  auto rdB = [&](char* l, int n, int cx) { return *(const bf16x8*)(l + rbB + (n << 11) + cx); };

  bf16x8 A0[2][2], B0[2][2], A0n[2][2], B0n[2][2];

  stA(0, 0, LA0); stA(0, 1, LA0); stA(0, 2, LA0); stA(0, 3, LA0);
  stB(0, 0, LB0); stB(0, 1, LB0);
  stB(1, 0, LB1); stB(1, 1, LB1);
  asm volatile("s_waitcnt vmcnt(2)" ::: "memory");
  __builtin_amdgcn_s_barrier();
#pragma unroll
  for (int n = 0; n < 2; ++n) { B0[n][0] = rdB(LB0, n, cx0); B0[n][1] = rdB(LB0, n, cx1); }
#pragma unroll
  for (int m = 0; m < 2; ++m) { A0[m][0] = rdA(LA0, m, cx0); A0[m][1] = rdA(LA0, m, cx1); }

  auto tile = [&](char* lA, char* lB, char* lAn, char* lBn, int t,
                  bf16x8 (&a0)[2][2], bf16x8 (&b0)[2][2],
                  bf16x8 (&a0n)[2][2], bf16x8 (&b0n)[2][2]) {
    bf16x8 a1[2][2], b1[2][2];
    // ph0
#pragma unroll
    for (int n = 0; n < 2; ++n) { b1[n][0] = rdB(lB, n + 2, cx0); b1[n][1] = rdB(lB, n + 2, cx1); }
    stA(t + 1, 0, lAn); stA(t + 1, 1, lAn);
    __builtin_amdgcn_s_barrier();
    asm volatile("s_waitcnt lgkmcnt(4)" ::: "memory");
    __builtin_amdgcn_sched_barrier(0);
    __builtin_amdgcn_s_setprio(1);
#pragma unroll
    for (int m = 0; m < 2; ++m)
#pragma unroll
      for (int n = 0; n < 2; ++n) {
        acc[m][n] = mfma16x16x32(a0[m][0], b0[n][0], acc[m][n]);
        acc[m][n] = mfma16x16x32(a0[m][1], b0[n][1], acc[m][n]);
      }
    __builtin_amdgcn_s_setprio(0);
    __builtin_amdgcn_s_barrier();
    // ph1
#pragma unroll
    for (int m = 0; m < 2; ++m) { a1[m][0] = rdA(lA, m + 2, cx0); a1[m][1] = rdA(lA, m + 2, cx1); }
    stA(t + 1, 2, lAn); stA(t + 1, 3, lAn);
    asm volatile("s_waitcnt vmcnt(4)" ::: "memory");
    __builtin_amdgcn_s_barrier();
    asm volatile("s_waitcnt lgkmcnt(4)" ::: "memory");
    __builtin_amdgcn_sched_barrier(0);
    __builtin_amdgcn_s_setprio(1);
#pragma unroll
    for (int m = 0; m < 2; ++m)
#pragma unroll
      for (int n = 0; n < 2; ++n) {
        acc[m][n + 2] = mfma16x16x32(a0[m][0], b1[n][0], acc[m][n + 2]);
        acc[m][n + 2] = mfma16x16x32(a0[m][1], b1[n][1], acc[m][n + 2]);
      }
    __builtin_amdgcn_s_setprio(0);
    __builtin_amdgcn_s_barrier();
    // ph2
#pragma unroll
    for (int n = 0; n < 2; ++n) { b0n[n][0] = rdB(lBn, n, cx0); b0n[n][1] = rdB(lBn, n, cx1); }
    stB(t + 2, 0, lB); stB(t + 2, 1, lB);
    asm volatile("s_waitcnt vmcnt(2)" ::: "memory");
    __builtin_amdgcn_s_barrier();
    asm volatile("s_waitcnt lgkmcnt(4)" ::: "memory");
    __builtin_amdgcn_sched_barrier(0);
    __builtin_amdgcn_s_setprio(1);
#pragma unroll
    for (int m = 0; m < 2; ++m)
#pragma unroll
      for (int n = 0; n < 2; ++n) {
        acc[m + 2][n] = mfma16x16x32(a1[m][0], b0[n][0], acc[m + 2][n]);
        acc[m + 2][n] = mfma16x16x32(a1[m][1], b0[n][1], acc[m + 2][n]);
      }
    __builtin_amdgcn_s_setprio(0);
    __builtin_amdgcn_s_barrier();
    // ph3
#pragma unroll
    for (int m = 0; m < 2; ++m) { a0n[m][0] = rdA(lAn, m, cx0); a0n[m][1] = rdA(lAn, m, cx1); }
    __builtin_amdgcn_s_barrier();
    asm volatile("s_waitcnt lgkmcnt(4)" ::: "memory");
    __builtin_amdgcn_sched_barrier(0);
    __builtin_amdgcn_s_setprio(1);
#pragma unroll
    for (int m = 0; m < 2; ++m)
#pragma unroll
      for (int n = 0; n < 2; ++n) {
        acc[m + 2][n + 2] = mfma16x16x32(a1[m][0], b1[n][0], acc[m + 2][n + 2]);
        acc[m + 2][n + 2] = mfma16x16x32(a1[m][1], b1[n][1], acc[m + 2][n + 2]);
      }
    __builtin_amdgcn_s_setprio(0);
    __builtin_amdgcn_s_barrier();
  };

  for (int t = 0; t < NT; t += 2) {
    tile(LA0, LB0, LA1, LB1, t,     A0, B0, A0n, B0n);
    tile(LA1, LB1, LA0, LB0, t + 1, A0n, B0n, A0, B0);
  }
  asm volatile("s_waitcnt vmcnt(0)" ::: "memory");
}

// ---------------- scores = [Qh|Qh|Ql] . [Kh|Kl|Kh]^T, fp32 out ----------------
__global__ __launch_bounds__(512, 2)
void gemm256_scores(const __bf16* __restrict__ Qh, const __bf16* __restrict__ Ql,
                    const __bf16* __restrict__ Kh, const __bf16* __restrict__ Kl,
                    float* __restrict__ Sf) {
  extern __shared__ char smem[];
  int bx, by, bz; swz_xy(bx, by, bz);
  const size_t zo = (size_t)bz * SS * DD;
  const int row0 = by * 256, col0 = bx * 256;
  const size_t ra = zo + (size_t)row0 * DD, rb = zo + (size_t)col0 * DD;
  Segs s{Qh + ra, Qh + ra, Ql + ra, Kh + rb, Kl + rb, Kh + rb};
  f32x4 acc[8][4] = {};
  gemm256_core(s, 48, smem, acc);

  float* C = Sf + (size_t)bz * SS * SS;
  const int lane = threadIdx.x & 63, wave = threadIdx.x >> 6;
  const int wm = wave >> 2, wn = wave & 3;
#pragma unroll
  for (int m = 0; m < 8; ++m)
#pragma unroll
    for (int n = 0; n < 4; ++n) {
      int col = col0 + wn * 64 + n * 16 + (lane & 15);
      int rowb = row0 + wm * 128 + m * 16 + (lane >> 4) * 4;
#pragma unroll
      for (int j = 0; j < 4; ++j)
        C[(size_t)(rowb + j) * SS + col] = acc[m][n][j];
    }
}

// ---------------- fused Q+K projections, N-concat (256 blocks) -------
__global__ __launch_bounds__(512, 2)
void gemm256_projqk(const __bf16* __restrict__ xh, const __bf16* __restrict__ xl,
                    const __bf16* __restrict__ wqh, const __bf16* __restrict__ wql,
                    const __bf16* __restrict__ wkh, const __bf16* __restrict__ wkl,
                    const float* __restrict__ bq, const float* __restrict__ bk,
                    __bf16* __restrict__ Qh, __bf16* __restrict__ Ql,
                    __bf16* __restrict__ Kh, __bf16* __restrict__ Kl) {
  extern __shared__ char smem[];
  int bx, by, bz; swz_xy(bx, by, bz);
  const int row0 = by * 256;
  const int cg = bx;
  const bool isK = cg >= 4;
  const int col0 = (cg & 3) * 256;
  const __bf16* B0p = isK ? wkh : wqh;
  const __bf16* B1p = isK ? wkl : wql;
  const float* bias = isK ? bk : bq;
  __bf16* CH = isK ? Kh : Qh;
  __bf16* CL = isK ? Kl : Ql;

  const size_t ra = (size_t)row0 * DD, rb = (size_t)col0 * DD;
  Segs s{xh + ra, xh + ra, xl + ra, B0p + rb, B1p + rb, B0p + rb};
  f32x4 acc[8][4] = {};
  gemm256_core(s, 48, smem, acc);

  const int lane = threadIdx.x & 63, wave = threadIdx.x >> 6;
  const int wm = wave >> 2, wn = wave & 3;
#pragma unroll
  for (int m = 0; m < 8; ++m)
#pragma unroll
    for (int n = 0; n < 4; ++n) {
      int col = col0 + wn * 64 + n * 16 + (lane & 15);
      float bvv = bias[col];
      int rowb = row0 + wm * 128 + m * 16 + (lane >> 4) * 4;
#pragma unroll
      for (int j = 0; j < 4; ++j) {
        float v = acc[m][n][j] + bvv;
        size_t idx = (size_t)(rowb + j) * DD + col;
        __bf16 h = (__bf16)v;
        CH[idx] = h;
        CL[idx] = (__bf16)(v - (float)h);
      }
    }
}

// ---------------- Vt = Wv . x^T (256x128 core, 256 blocks) ----------------
__global__ __launch_bounds__(512, 2)
void gemm_vt128(const __bf16* __restrict__ wvh, const __bf16* __restrict__ xh,
                const float* __restrict__ bvv, __bf16* __restrict__ Vt) {
  extern __shared__ char smem[];
  int bx, by, bz; swz_xy(bx, by, bz);
  const int row0 = by * 256;  // d
  const int col0 = bx * 128;  // s global (0..8191)
  f32x4 acc[4][4] = {};
  gemm128_core(wvh + (size_t)row0 * DD, xh + (size_t)col0 * DD, DD, 16, smem, acc);

  const int lane = threadIdx.x & 63, wave = threadIdx.x >> 6;
  const int wm = wave >> 1, wn = wave & 1;
#pragma unroll
  for (int m = 0; m < 4; ++m)
#pragma unroll
    for (int n = 0; n < 4; ++n) {
      int col = col0 + wn * 64 + n * 16 + (lane & 15);
      int batch = col >> 12, sl = col & 4095;
      int rowb = row0 + wm * 64 + m * 16 + (lane >> 4) * 4;
#pragma unroll
      for (int j = 0; j < 4; ++j) {
        float v = acc[m][n][j] + bvv[rowb + j];
        Vt[(size_t)batch * DD * SS + (size_t)(rowb + j) * SS + sl] = (__bf16)v;
      }
    }
}

// ---------------- out = attn @ V (256x128 core, 256 blocks) ----------------
__global__ __launch_bounds__(512, 2)
void gemm_pv128(const __bf16* __restrict__ Pb, const __bf16* __restrict__ Vt,
                float* __restrict__ out) {
  extern __shared__ char smem[];
  int bx, by, bz; swz_xy(bx, by, bz);
  const int row0 = by * 256;  // q
  const int col0 = bx * 128;  // d
  f32x4 acc[4][4] = {};
  gemm128_core(Pb + (size_t)bz * SS * SS + (size_t)row0 * SS,
               Vt + (size_t)bz * DD * SS + (size_t)col0 * SS,
               SS, 64, smem, acc);

  float* C = out + (size_t)bz * SS * DD;
  const int lane = threadIdx.x & 63, wave = threadIdx.x >> 6;
  const int wm = wave >> 1, wn = wave & 1;
#pragma unroll
  for (int m = 0; m < 4; ++m)
#pragma unroll
    for (int n = 0; n < 4; ++n) {
      int col = col0 + wn * 64 + n * 16 + (lane & 15);
      int rowb = row0 + wm * 64 + m * 16 + (lane >> 4) * 4;
#pragma unroll
      for (int j = 0; j < 4; ++j)
        C[(size_t)(rowb + j) * DD + col] = acc[m][n][j];
    }
}

// ---------------- fused splits: x, Wq, Wk, Wv in one dispatch ----------------
__global__ __launch_bounds__(256)
void split_all(const float* __restrict__ x, const float* __restrict__ Wq,
               const float* __restrict__ Wk, const float* __restrict__ Wv,
               __bf16* __restrict__ xh, __bf16* __restrict__ xl,
               __bf16* __restrict__ wqh, __bf16* __restrict__ wql,
               __bf16* __restrict__ wkh, __bf16* __restrict__ wkl,
               __bf16* __restrict__ wvh) {
  const int b = blockIdx.x, tid = threadIdx.x;
  const float* in; __bf16 *hi, *lo; int nv, rb, nb;
  if (b < 1536)      { in = x;  hi = xh;  lo = xl;  nv = (MROWS * DD) >> 2; rb = b;        nb = 1536; }
  else if (b < 1792) { in = Wq; hi = wqh; lo = wql; nv = (DD * DD) >> 2;    rb = b - 1536; nb = 256; }
  else if (b < 2048) { in = Wk; hi = wkh; lo = wkl; nv = (DD * DD) >> 2;    rb = b - 1792; nb = 256; }
  else               { in = Wv; hi = wvh; lo = nullptr; nv = (DD * DD) >> 2; rb = b - 2048; nb = 256; }
  for (int i = rb * 256 + tid; i < nv; i += nb * 256) {
    f32x4 v = *(const f32x4*)(in + (size_t)i * 4);
    bf16x4 h, l;
#pragma unroll
    for (int e = 0; e < 4; ++e) {
      __bf16 hh = (__bf16)v[e];
      h[e] = hh;
      l[e] = (__bf16)(v[e] - (float)hh);
    }
    *(bf16x4*)(hi + (size_t)i * 4) = h;
    if (lo) *(bf16x4*)(lo + (size_t)i * 4) = l;
  }
}

// ---------------- softmax + dropout ----------------
__global__ __launch_bounds__(256)
void softmax_dropout(const float* __restrict__ Sf, const float* __restrict__ U,
                     __bf16* __restrict__ P) {
  __shared__ float red[4];
  const size_t row = blockIdx.x;
  const float* s = Sf + row * SS;
  const float* u = U + row * SS;
  __bf16* p = P + row * SS;
  const int tid = threadIdx.x, lane = tid & 63, wave = tid >> 6;

  f32x4 v[4];
  float m = -3.0e38f;
#pragma unroll
  for (int j = 0; j < 4; ++j) {
    v[j] = *(const f32x4*)(s + (size_t)(j * 256 + tid) * 4);
#pragma unroll
    for (int e = 0; e < 4; ++e) m = fmaxf(m, v[j][e]);
  }
#pragma unroll
  for (int o = 32; o > 0; o >>= 1) m = fmaxf(m, __shfl_xor(m, o));
  if (lane == 0) red[wave] = m;
  __syncthreads();
  m = fmaxf(fmaxf(red[0], red[1]), fmaxf(red[2], red[3]));

  float sum = 0.0f;
#pragma unroll
  for (int j = 0; j < 4; ++j)
#pragma unroll
    for (int e = 0; e < 4; ++e) { float ex = __expf(v[j][e] - m); v[j][e] = ex; sum += ex; }
#pragma unroll
  for (int o = 32; o > 0; o >>= 1) sum += __shfl_xor(sum, o);
  __syncthreads();
  if (lane == 0) red[wave] = sum;
  __syncthreads();
  sum = red[0] + red[1] + red[2] + red[3];
  const float scale = 1.25f / sum;

#pragma unroll
  for (int j = 0; j < 4; ++j) {
    f32x4 uu = *(const f32x4*)(u + (size_t)(j * 256 + tid) * 4);
    bf16x4 out;
#pragma unroll
    for (int e = 0; e < 4; ++e)
      out[e] = (__bf16)((uu[e] >= 0.2f) ? v[j][e] * scale : 0.0f);
    *(bf16x4*)(p + (size_t)(j * 256 + tid) * 4) = out;
  }
}

// ---------------- launcher ----------------
extern "C" void kernel_launch(void* const* d_in, const int* in_sizes, int n_in,
                              void* d_out, int out_size, void* d_ws, size_t ws_size,
                              hipStream_t stream) {
  if (ws_size < WS_NEEDED) return;

  const float* x  = (const float*)d_in[0];
  const float* Wq = (const float*)d_in[1];
  const float* bq = (const float*)d_in[2];
  const float* Wk = (const float*)d_in[3];
  const float* bk = (const float*)d_in[4];
  const float* Wv = (const float*)d_in[5];
  const float* bv = (const float*)d_in[6];
  const float* du = (const float*)d_in[7];

  char* ws = (char*)d_ws;
  __bf16* Vt  = (__bf16*)(ws + O_VT);
  __bf16* Pb  = (__bf16*)(ws + O_ATTN);
  __bf16* Qh  = (__bf16*)(ws + O_QH);
  __bf16* Ql  = (__bf16*)(ws + O_QL);
  __bf16* Kh  = (__bf16*)(ws + O_KH);
  __bf16* Kl  = (__bf16*)(ws + O_KL);
  float*  Sf  = (float*) (ws + O_S);
  __bf16* xh  = (__bf16*)(ws + O_XH);
  __bf16* xl  = (__bf16*)(ws + O_XL);
  __bf16* wqh = (__bf16*)(ws + O_WQH);
  __bf16* wql = (__bf16*)(ws + O_WQL);
  __bf16* wkh = (__bf16*)(ws + O_WKH);
  __bf16* wkl = (__bf16*)(ws + O_WKL);
  __bf16* wvh = (__bf16*)(ws + O_WVH);
  float*  out = (float*)d_out;

  hipFuncSetAttribute((const void*)gemm256_scores,
                      hipFuncAttributeMaxDynamicSharedMemorySize, 131072);
  hipFuncSetAttribute((const void*)gemm256_projqk,
                      hipFuncAttributeMaxDynamicSharedMemorySize, 131072);
  hipFuncSetAttribute((const void*)gemm_vt128,
                      hipFuncAttributeMaxDynamicSharedMemorySize, 98304);
  hipFuncSetAttribute((const void*)gemm_pv128,
                      hipFuncAttributeMaxDynamicSharedMemorySize, 98304);

  // 1) splits (one dispatch)
  split_all<<<2304, 256, 0, stream>>>(x, Wq, Wk, Wv, xh, xl, wqh, wql, wkh, wkl, wvh);

  // 2) Q+K projections (256 blocks)
  gemm256_projqk<<<dim3(8, MROWS / 256), 512, 131072, stream>>>(
      xh, xl, wqh, wql, wkh, wkl, bq, bk, Qh, Ql, Kh, Kl);

  // 3) Vt = Wv . x^T + bv (256 blocks)
  gemm_vt128<<<dim3(MROWS / 128, DD / 256), 512, 98304, stream>>>(wvh, xh, bv, Vt);

  // 4) scores = Q K^T (split via K-concat, fp32 out)
  gemm256_scores<<<dim3(SS / 256, SS / 256, BB), 512, 131072, stream>>>(Qh, Ql, Kh, Kl, Sf);

  // 5) softmax + dropout -> attn bf16
  softmax_dropout<<<MROWS, 256, 0, stream>>>(Sf, du, Pb);

  // 6) out = attn @ V (256 blocks)
  gemm_pv128<<<dim3(DD / 128, SS / 256, BB), 512, 98304, stream>>>(Pb, Vt, out);
}

// Round 7
// 366.641 us; speedup vs baseline: 1.6380x; 1.6380x over previous
//
#include <hip/hip_runtime.h>

typedef float    f32x4 __attribute__((ext_vector_type(4)));
typedef _Float16 f16x8 __attribute__((ext_vector_type(8)));
typedef _Float16 f16x4 __attribute__((ext_vector_type(4)));
typedef _Float16 f16;

#define DEVFN static __device__ __forceinline__

constexpr int BB = 2, SS = 4096, DD = 1024;
constexpr int MROWS = BB * SS; // 8192

// ---------------- workspace layout (bytes) ----------------
constexpr size_t SZ_QK   = (size_t)MROWS * DD * 2;
constexpr size_t SZ_VT   = (size_t)BB * DD * SS * 2;
constexpr size_t SZ_ATTN = (size_t)BB * SS * SS * 2;
constexpr size_t SZ_S    = (size_t)BB * SS * SS * 4;
constexpr size_t SZ_W    = (size_t)DD * DD * 2;

constexpr size_t O_VT   = 0;
constexpr size_t O_ATTN = O_VT + SZ_VT;
constexpr size_t O_Q    = O_ATTN;            // Q fp16, dead after scores
constexpr size_t O_K    = O_Q + 2 * SZ_QK;   // K fp16, dead after scores
constexpr size_t O_S    = O_ATTN + SZ_ATTN;  // f32 scores
constexpr size_t O_XH   = O_S;               // phase-1 aliases in scores region
constexpr size_t O_XL   = O_XH + SZ_QK;
constexpr size_t O_WQH  = O_XL + SZ_QK;
constexpr size_t O_WQL  = O_WQH + SZ_W;
constexpr size_t O_WKH  = O_WQL + SZ_W;
constexpr size_t O_WKL  = O_WKH + SZ_W;
constexpr size_t O_WVH  = O_WKL + SZ_W;
constexpr size_t WS_NEEDED = SZ_VT + SZ_ATTN + SZ_S;

// ---------------- helpers ----------------
DEVFN f32x4 mfma16x16x32(f16x8 a, f16x8 b, f32x4 c) {
  return __builtin_amdgcn_mfma_f32_16x16x32_f16(a, b, c, 0, 0, 0);
}

DEVFN void gld16(const f16* g, char* l) {
  __builtin_amdgcn_global_load_lds((const __attribute__((address_space(1))) void*)g,
                                   (__attribute__((address_space(3))) void*)l, 16, 0, 0);
}

// bijective XCD-chunked block swizzle (requires total blocks % 8 == 0)
DEVFN void swz_xy(int& bx, int& by, int& bz) {
  const int gx = gridDim.x, gy = gridDim.y, gz = gridDim.z;
  const int lin = (blockIdx.z * gy + blockIdx.y) * gx + blockIdx.x;
  const int chunk = (gx * gy * gz) >> 3;
  const int nl = (lin & 7) * chunk + (lin >> 3);
  bx = nl % gx; const int r = nl / gx; by = r % gy; bz = r / gy;
}

// =====================================================================
// 256x256 8-phase GEMM core (R4 version — counted vmcnt, never drain-0).
// Reads:  ph0: b1(cur) | ph1: a1(cur) | ph2: b0'(nxt) | ph3: a0'(nxt)
// MFMA:   ph0: a0*b0   | ph1: a0*b1   | ph2: a1*b0    | ph3: a1*b1
// Stages: ph0: A(u+1)q0,q2 | ph1: A(u+1)q1,q3 | ph2: B(u+2)q0,q1 | ph3: B(u+2)q2,q3
// =====================================================================
struct Segs { const f16 *a0, *a1, *a2, *b0, *b1, *b2; };

DEVFN void gemm256_core(Segs s, int NT, char* smem, f32x4 (&acc)[8][4]) {
  const int tid = threadIdx.x, lane = tid & 63, wave = tid >> 6;
  const int wm = wave >> 2, wn = wave & 3;
  const size_t rk = (size_t)((wave << 3) + (lane >> 3)) * DD +
                    (size_t)((((lane & 7) ^ (lane >> 3)) << 3));
  const int wvoff = wave << 10;
  const int rbA = (((wm << 7) + (lane & 15)) << 7);
  const int rbB = (((wn << 6) + (lane & 15)) << 7);
  const int cx0 = (((lane >> 4) << 4)) ^ ((lane & 7) << 4);
  const int cx1 = cx0 ^ 64;

  char* LA0 = smem;
  char* LB0 = smem + 32768;
  char* LA1 = smem + 65536;
  char* LB1 = smem + 98304;

  auto stA = [&](int u, int q, char* dst) {
    int uc = (u < NT) ? u : (NT - 1);
    int sg = uc >> 4;
    const f16* p = (sg == 0) ? s.a0 : ((sg == 1) ? s.a1 : s.a2);
    gld16(p + ((size_t)(q << 6)) * DD + ((uc & 15) << 6) + rk, dst + (q << 13) + wvoff);
  };
  auto stB = [&](int u, int q, char* dst) {
    int uc = (u < NT) ? u : (NT - 1);
    int sg = uc >> 4;
    const f16* p = (sg == 0) ? s.b0 : ((sg == 1) ? s.b1 : s.b2);
    gld16(p + ((size_t)(q << 6)) * DD + ((uc & 15) << 6) + rk, dst + (q << 13) + wvoff);
  };
  auto rdA = [&](char* l, int m, int cx) { return *(const f16x8*)(l + rbA + (m << 11) + cx); };
  auto rdB = [&](char* l, int n, int cx) { return *(const f16x8*)(l + rbB + (n << 11) + cx); };

  f16x8 A0[4][2], B0[2][2], A0n[4][2], B0n[2][2];

  stB(0, 0, LB0); stB(0, 1, LB0);
  stB(0, 2, LB0); stB(0, 3, LB0);
  stA(0, 0, LA0); stA(0, 2, LA0);
  stA(0, 1, LA0); stA(0, 3, LA0);
  stB(1, 0, LB1); stB(1, 1, LB1);
  stB(1, 2, LB1); stB(1, 3, LB1);
  asm volatile("s_waitcnt vmcnt(6)" ::: "memory");
  __builtin_amdgcn_s_barrier();
#pragma unroll
  for (int n = 0; n < 2; ++n) { B0[n][0] = rdB(LB0, n, cx0); B0[n][1] = rdB(LB0, n, cx1); }
#pragma unroll
  for (int m = 0; m < 4; ++m) { A0[m][0] = rdA(LA0, m, cx0); A0[m][1] = rdA(LA0, m, cx1); }

  auto tile = [&](char* lA, char* lB, char* lAn, char* lBn, int t,
                  f16x8 (&a0)[4][2], f16x8 (&b0)[2][2],
                  f16x8 (&a0n)[4][2], f16x8 (&b0n)[2][2]) {
    f16x8 a1[4][2], b1[2][2];
    // ph0
#pragma unroll
    for (int n = 0; n < 2; ++n) { b1[n][0] = rdB(lB, n + 2, cx0); b1[n][1] = rdB(lB, n + 2, cx1); }
    stA(t + 1, 0, lAn); stA(t + 1, 2, lAn);
    asm volatile("s_waitcnt vmcnt(4)" ::: "memory");
    __builtin_amdgcn_s_barrier();
    asm volatile("s_waitcnt lgkmcnt(4)" ::: "memory");
    __builtin_amdgcn_sched_barrier(0);
    __builtin_amdgcn_s_setprio(1);
#pragma unroll
    for (int m = 0; m < 4; ++m)
#pragma unroll
      for (int n = 0; n < 2; ++n) {
        acc[m][n] = mfma16x16x32(a0[m][0], b0[n][0], acc[m][n]);
        acc[m][n] = mfma16x16x32(a0[m][1], b0[n][1], acc[m][n]);
      }
    __builtin_amdgcn_s_setprio(0);
    __builtin_amdgcn_s_barrier();
    // ph1
#pragma unroll
    for (int m = 0; m < 4; ++m) { a1[m][0] = rdA(lA, m + 4, cx0); a1[m][1] = rdA(lA, m + 4, cx1); }
    stA(t + 1, 1, lAn); stA(t + 1, 3, lAn);
    asm volatile("s_waitcnt vmcnt(4)" ::: "memory");
    __builtin_amdgcn_s_barrier();
    asm volatile("s_waitcnt lgkmcnt(8)" ::: "memory");
    __builtin_amdgcn_sched_barrier(0);
    __builtin_amdgcn_s_setprio(1);
#pragma unroll
    for (int m = 0; m < 4; ++m)
#pragma unroll
      for (int n = 0; n < 2; ++n) {
        acc[m][n + 2] = mfma16x16x32(a0[m][0], b1[n][0], acc[m][n + 2]);
        acc[m][n + 2] = mfma16x16x32(a0[m][1], b1[n][1], acc[m][n + 2]);
      }
    __builtin_amdgcn_s_setprio(0);
    __builtin_amdgcn_s_barrier();
    // ph2
#pragma unroll
    for (int n = 0; n < 2; ++n) { b0n[n][0] = rdB(lBn, n, cx0); b0n[n][1] = rdB(lBn, n, cx1); }
    stB(t + 2, 0, lB); stB(t + 2, 1, lB);
    asm volatile("s_waitcnt vmcnt(4)" ::: "memory");
    __builtin_amdgcn_s_barrier();
    asm volatile("s_waitcnt lgkmcnt(4)" ::: "memory");
    __builtin_amdgcn_sched_barrier(0);
    __builtin_amdgcn_s_setprio(1);
#pragma unroll
    for (int m = 0; m < 4; ++m)
#pragma unroll
      for (int n = 0; n < 2; ++n) {
        acc[m + 4][n] = mfma16x16x32(a1[m][0], b0[n][0], acc[m + 4][n]);
        acc[m + 4][n] = mfma16x16x32(a1[m][1], b0[n][1], acc[m + 4][n]);
      }
    __builtin_amdgcn_s_setprio(0);
    __builtin_amdgcn_s_barrier();
    // ph3
#pragma unroll
    for (int m = 0; m < 4; ++m) { a0n[m][0] = rdA(lAn, m, cx0); a0n[m][1] = rdA(lAn, m, cx1); }
    stB(t + 2, 2, lB); stB(t + 2, 3, lB);
    asm volatile("s_waitcnt vmcnt(4)" ::: "memory");
    __builtin_amdgcn_s_barrier();
    asm volatile("s_waitcnt lgkmcnt(8)" ::: "memory");
    __builtin_amdgcn_sched_barrier(0);
    __builtin_amdgcn_s_setprio(1);
#pragma unroll
    for (int m = 0; m < 4; ++m)
#pragma unroll
      for (int n = 0; n < 2; ++n) {
        acc[m + 4][n + 2] = mfma16x16x32(a1[m][0], b1[n][0], acc[m + 4][n + 2]);
        acc[m + 4][n + 2] = mfma16x16x32(a1[m][1], b1[n][1], acc[m + 4][n + 2]);
      }
    __builtin_amdgcn_s_setprio(0);
    __builtin_amdgcn_s_barrier();
  };

  for (int t = 0; t < NT; t += 2) {
    tile(LA0, LB0, LA1, LB1, t,     A0,  B0,  A0n, B0n);
    tile(LA1, LB1, LA0, LB0, t + 1, A0n, B0n, A0,  B0);
  }
  asm volatile("s_waitcnt vmcnt(0)" ::: "memory");
}

// =====================================================================
// 256x128 8-phase GEMM core (R5 version, fp16)
// =====================================================================
DEVFN void gemm128_core(const f16* Ap, const f16* Bp, size_t ld, int NT,
                        char* smem, f32x4 (&acc)[4][4]) {
  const int tid = threadIdx.x, lane = tid & 63, wave = tid >> 6;
  const int wm = wave >> 1, wn = wave & 1;
  const size_t rk = (size_t)(tid >> 3) * ld +
                    (size_t)((((lane & 7) ^ (lane >> 3)) << 3));
  const int wvoff = wave << 10;
  const int rbA = (((wm << 6) + (lane & 15)) << 7);
  const int rbB = (((wn << 6) + (lane & 15)) << 7);
  const int cx0 = (((lane >> 4) << 4)) ^ ((lane & 7) << 4);
  const int cx1 = cx0 ^ 64;

  char* LA0 = smem;
  char* LB0 = smem + 32768;
  char* LA1 = smem + 49152;
  char* LB1 = smem + 81920;

  auto stA = [&](int u, int q, char* dst) {
    int uc = (u < NT) ? u : (NT - 1);
    gld16(Ap + (size_t)(q << 6) * ld + ((size_t)uc << 6) + rk, dst + (q << 13) + wvoff);
  };
  auto stB = [&](int u, int q, char* dst) {
    int uc = (u < NT) ? u : (NT - 1);
    gld16(Bp + (size_t)(q << 6) * ld + ((size_t)uc << 6) + rk, dst + (q << 13) + wvoff);
  };
  auto rdA = [&](char* l, int m, int cx) { return *(const f16x8*)(l + rbA + (m << 11) + cx); };
  auto rdB = [&](char* l, int n, int cx) { return *(const f16x8*)(l + rbB + (n << 11) + cx); };

  f16x8 A0[2][2], B0[2][2], A0n[2][2], B0n[2][2];

  stA(0, 0, LA0); stA(0, 1, LA0); stA(0, 2, LA0); stA(0, 3, LA0);
  stB(0, 0, LB0); stB(0, 1, LB0);
  stB(1, 0, LB1); stB(1, 1, LB1);
  asm volatile("s_waitcnt vmcnt(2)" ::: "memory");
  __builtin_amdgcn_s_barrier();
#pragma unroll
  for (int n = 0; n < 2; ++n) { B0[n][0] = rdB(LB0, n, cx0); B0[n][1] = rdB(LB0, n, cx1); }
#pragma unroll
  for (int m = 0; m < 2; ++m) { A0[m][0] = rdA(LA0, m, cx0); A0[m][1] = rdA(LA0, m, cx1); }

  auto tile = [&](char* lA, char* lB, char* lAn, char* lBn, int t,
                  f16x8 (&a0)[2][2], f16x8 (&b0)[2][2],
                  f16x8 (&a0n)[2][2], f16x8 (&b0n)[2][2]) {
    f16x8 a1[2][2], b1[2][2];
    // ph0
#pragma unroll
    for (int n = 0; n < 2; ++n) { b1[n][0] = rdB(lB, n + 2, cx0); b1[n][1] = rdB(lB, n + 2, cx1); }
    stA(t + 1, 0, lAn); stA(t + 1, 1, lAn);
    __builtin_amdgcn_s_barrier();
    asm volatile("s_waitcnt lgkmcnt(4)" ::: "memory");
    __builtin_amdgcn_sched_barrier(0);
    __builtin_amdgcn_s_setprio(1);
#pragma unroll
    for (int m = 0; m < 2; ++m)
#pragma unroll
      for (int n = 0; n < 2; ++n) {
        acc[m][n] = mfma16x16x32(a0[m][0], b0[n][0], acc[m][n]);
        acc[m][n] = mfma16x16x32(a0[m][1], b0[n][1], acc[m][n]);
      }
    __builtin_amdgcn_s_setprio(0);
    __builtin_amdgcn_s_barrier();
    // ph1
#pragma unroll
    for (int m = 0; m < 2; ++m) { a1[m][0] = rdA(lA, m + 2, cx0); a1[m][1] = rdA(lA, m + 2, cx1); }
    stA(t + 1, 2, lAn); stA(t + 1, 3, lAn);
    asm volatile("s_waitcnt vmcnt(4)" ::: "memory");
    __builtin_amdgcn_s_barrier();
    asm volatile("s_waitcnt lgkmcnt(4)" ::: "memory");
    __builtin_amdgcn_sched_barrier(0);
    __builtin_amdgcn_s_setprio(1);
#pragma unroll
    for (int m = 0; m < 2; ++m)
#pragma unroll
      for (int n = 0; n < 2; ++n) {
        acc[m][n + 2] = mfma16x16x32(a0[m][0], b1[n][0], acc[m][n + 2]);
        acc[m][n + 2] = mfma16x16x32(a0[m][1], b1[n][1], acc[m][n + 2]);
      }
    __builtin_amdgcn_s_setprio(0);
    __builtin_amdgcn_s_barrier();
    // ph2
#pragma unroll
    for (int n = 0; n < 2; ++n) { b0n[n][0] = rdB(lBn, n, cx0); b0n[n][1] = rdB(lBn, n, cx1); }
    stB(t + 2, 0, lB); stB(t + 2, 1, lB);
    asm volatile("s_waitcnt vmcnt(2)" ::: "memory");
    __builtin_amdgcn_s_barrier();
    asm volatile("s_waitcnt lgkmcnt(4)" ::: "memory");
    __builtin_amdgcn_sched_barrier(0);
    __builtin_amdgcn_s_setprio(1);
#pragma unroll
    for (int m = 0; m < 2; ++m)
#pragma unroll
      for (int n = 0; n < 2; ++n) {
        acc[m + 2][n] = mfma16x16x32(a1[m][0], b0[n][0], acc[m + 2][n]);
        acc[m + 2][n] = mfma16x16x32(a1[m][1], b0[n][1], acc[m + 2][n]);
      }
    __builtin_amdgcn_s_setprio(0);
    __builtin_amdgcn_s_barrier();
    // ph3
#pragma unroll
    for (int m = 0; m < 2; ++m) { a0n[m][0] = rdA(lAn, m, cx0); a0n[m][1] = rdA(lAn, m, cx1); }
    __builtin_amdgcn_s_barrier();
    asm volatile("s_waitcnt lgkmcnt(4)" ::: "memory");
    __builtin_amdgcn_sched_barrier(0);
    __builtin_amdgcn_s_setprio(1);
#pragma unroll
    for (int m = 0; m < 2; ++m)
#pragma unroll
      for (int n = 0; n < 2; ++n) {
        acc[m + 2][n + 2] = mfma16x16x32(a1[m][0], b1[n][0], acc[m + 2][n + 2]);
        acc[m + 2][n + 2] = mfma16x16x32(a1[m][1], b1[n][1], acc[m + 2][n + 2]);
      }
    __builtin_amdgcn_s_setprio(0);
    __builtin_amdgcn_s_barrier();
  };

  for (int t = 0; t < NT; t += 2) {
    tile(LA0, LB0, LA1, LB1, t,     A0, B0, A0n, B0n);
    tile(LA1, LB1, LA0, LB0, t + 1, A0n, B0n, A0, B0);
  }
  asm volatile("s_waitcnt vmcnt(0)" ::: "memory");
}

// ---------------- scores = Q . K^T (single-pass fp16, fp32 out) ----------------
__global__ __launch_bounds__(512, 2)
void gemm256_scores(const f16* __restrict__ Q, const f16* __restrict__ K,
                    float* __restrict__ Sf) {
  extern __shared__ char smem[];
  int bx, by, bz; swz_xy(bx, by, bz);
  const size_t zo = (size_t)bz * SS * DD;
  const int row0 = by * 256, col0 = bx * 256;
  const size_t ra = zo + (size_t)row0 * DD, rb = zo + (size_t)col0 * DD;
  Segs s{Q + ra, Q + ra, Q + ra, K + rb, K + rb, K + rb};
  f32x4 acc[8][4] = {};
  gemm256_core(s, 16, smem, acc);

  float* C = Sf + (size_t)bz * SS * SS;
  const int lane = threadIdx.x & 63, wave = threadIdx.x >> 6;
  const int wm = wave >> 2, wn = wave & 3;
#pragma unroll
  for (int m = 0; m < 8; ++m)
#pragma unroll
    for (int n = 0; n < 4; ++n) {
      int col = col0 + wn * 64 + n * 16 + (lane & 15);
      int rowb = row0 + wm * 128 + m * 16 + (lane >> 4) * 4;
#pragma unroll
      for (int j = 0; j < 4; ++j)
        C[(size_t)(rowb + j) * SS + col] = acc[m][n][j];
    }
}

// ---------------- fused Q+K projections, 3-pass split, fp16 out -------
__global__ __launch_bounds__(512, 2)
void gemm256_projqk(const f16* __restrict__ xh, const f16* __restrict__ xl,
                    const f16* __restrict__ wqh, const f16* __restrict__ wql,
                    const f16* __restrict__ wkh, const f16* __restrict__ wkl,
                    const float* __restrict__ bq, const float* __restrict__ bk,
                    f16* __restrict__ Q, f16* __restrict__ K) {
  extern __shared__ char smem[];
  int bx, by, bz; swz_xy(bx, by, bz);
  const int row0 = by * 256;
  const int cg = bx;                  // 0..3 = Q cols, 4..7 = K cols
  const bool isK = cg >= 4;
  const int col0 = (cg & 3) * 256;
  const f16* B0p = isK ? wkh : wqh;
  const f16* B1p = isK ? wkl : wql;
  const float* bias = isK ? bk : bq;
  f16* CH = isK ? K : Q;

  const size_t ra = (size_t)row0 * DD, rb = (size_t)col0 * DD;
  Segs s{xh + ra, xh + ra, xl + ra, B0p + rb, B1p + rb, B0p + rb};
  f32x4 acc[8][4] = {};
  gemm256_core(s, 48, smem, acc);

  const int lane = threadIdx.x & 63, wave = threadIdx.x >> 6;
  const int wm = wave >> 2, wn = wave & 3;
#pragma unroll
  for (int m = 0; m < 8; ++m)
#pragma unroll
    for (int n = 0; n < 4; ++n) {
      int col = col0 + wn * 64 + n * 16 + (lane & 15);
      float bvv = bias[col];
      int rowb = row0 + wm * 128 + m * 16 + (lane >> 4) * 4;
#pragma unroll
      for (int j = 0; j < 4; ++j)
        CH[(size_t)(rowb + j) * DD + col] = (f16)(acc[m][n][j] + bvv);
    }
}

// ---------------- Vt = Wv . x^T (256x128 core, 256 blocks) ----------------
__global__ __launch_bounds__(512, 2)
void gemm_vt128(const f16* __restrict__ wvh, const f16* __restrict__ xh,
                const float* __restrict__ bvv, f16* __restrict__ Vt) {
  extern __shared__ char smem[];
  int bx, by, bz; swz_xy(bx, by, bz);
  const int row0 = by * 256;  // d
  const int col0 = bx * 128;  // s global (0..8191)
  f32x4 acc[4][4] = {};
  gemm128_core(wvh + (size_t)row0 * DD, xh + (size_t)col0 * DD, DD, 16, smem, acc);

  const int lane = threadIdx.x & 63, wave = threadIdx.x >> 6;
  const int wm = wave >> 1, wn = wave & 1;
#pragma unroll
  for (int m = 0; m < 4; ++m)
#pragma unroll
    for (int n = 0; n < 4; ++n) {
      int col = col0 + wn * 64 + n * 16 + (lane & 15);
      int batch = col >> 12, sl = col & 4095;
      int rowb = row0 + wm * 64 + m * 16 + (lane >> 4) * 4;
#pragma unroll
      for (int j = 0; j < 4; ++j) {
        float v = acc[m][n][j] + bvv[rowb + j];
        Vt[(size_t)batch * DD * SS + (size_t)(rowb + j) * SS + sl] = (f16)v;
      }
    }
}

// ---------------- out = attn @ V (256x128 core, 256 blocks) ----------------
__global__ __launch_bounds__(512, 2)
void gemm_pv128(const f16* __restrict__ Pb, const f16* __restrict__ Vt,
                float* __restrict__ out) {
  extern __shared__ char smem[];
  int bx, by, bz; swz_xy(bx, by, bz);
  const int row0 = by * 256;  // q
  const int col0 = bx * 128;  // d
  f32x4 acc[4][4] = {};
  gemm128_core(Pb + (size_t)bz * SS * SS + (size_t)row0 * SS,
               Vt + (size_t)bz * DD * SS + (size_t)col0 * SS,
               SS, 64, smem, acc);

  float* C = out + (size_t)bz * SS * DD;
  const int lane = threadIdx.x & 63, wave = threadIdx.x >> 6;
  const int wm = wave >> 1, wn = wave & 1;
#pragma unroll
  for (int m = 0; m < 4; ++m)
#pragma unroll
    for (int n = 0; n < 4; ++n) {
      int col = col0 + wn * 64 + n * 16 + (lane & 15);
      int rowb = row0 + wm * 64 + m * 16 + (lane >> 4) * 4;
#pragma unroll
      for (int j = 0; j < 4; ++j)
        C[(size_t)(rowb + j) * DD + col] = acc[m][n][j];
    }
}

// ---------------- fused splits: x, Wq, Wk, Wv in one dispatch (fp16 hi/lo) ------
__global__ __launch_bounds__(256)
void split_all(const float* __restrict__ x, const float* __restrict__ Wq,
               const float* __restrict__ Wk, const float* __restrict__ Wv,
               f16* __restrict__ xh, f16* __restrict__ xl,
               f16* __restrict__ wqh, f16* __restrict__ wql,
               f16* __restrict__ wkh, f16* __restrict__ wkl,
               f16* __restrict__ wvh) {
  const int b = blockIdx.x, tid = threadIdx.x;
  const float* in; f16 *hi, *lo; int nv, rb, nb;
  if (b < 1536)      { in = x;  hi = xh;  lo = xl;  nv = (MROWS * DD) >> 2; rb = b;        nb = 1536; }
  else if (b < 1792) { in = Wq; hi = wqh; lo = wql; nv = (DD * DD) >> 2;    rb = b - 1536; nb = 256; }
  else if (b < 2048) { in = Wk; hi = wkh; lo = wkl; nv = (DD * DD) >> 2;    rb = b - 1792; nb = 256; }
  else               { in = Wv; hi = wvh; lo = nullptr; nv = (DD * DD) >> 2; rb = b - 2048; nb = 256; }
  for (int i = rb * 256 + tid; i < nv; i += nb * 256) {
    f32x4 v = *(const f32x4*)(in + (size_t)i * 4);
    f16x4 h, l;
#pragma unroll
    for (int e = 0; e < 4; ++e) {
      f16 hh = (f16)v[e];
      h[e] = hh;
      l[e] = (f16)(v[e] - (float)hh);
    }
    *(f16x4*)(hi + (size_t)i * 4) = h;
    if (lo) *(f16x4*)(lo + (size_t)i * 4) = l;
  }
}

// ---------------- softmax + dropout (fp16 out) ----------------
__global__ __launch_bounds__(256)
void softmax_dropout(const float* __restrict__ Sf, const float* __restrict__ U,
                     f16* __restrict__ P) {
  __shared__ float red[4];
  const size_t row = blockIdx.x;
  const float* s = Sf + row * SS;
  const float* u = U + row * SS;
  f16* p = P + row * SS;
  const int tid = threadIdx.x, lane = tid & 63, wave = tid >> 6;

  f32x4 v[4];
  float m = -3.0e38f;
#pragma unroll
  for (int j = 0; j < 4; ++j) {
    v[j] = *(const f32x4*)(s + (size_t)(j * 256 + tid) * 4);
#pragma unroll
    for (int e = 0; e < 4; ++e) m = fmaxf(m, v[j][e]);
  }
#pragma unroll
  for (int o = 32; o > 0; o >>= 1) m = fmaxf(m, __shfl_xor(m, o));
  if (lane == 0) red[wave] = m;
  __syncthreads();
  m = fmaxf(fmaxf(red[0], red[1]), fmaxf(red[2], red[3]));

  float sum = 0.0f;
#pragma unroll
  for (int j = 0; j < 4; ++j)
#pragma unroll
    for (int e = 0; e < 4; ++e) { float ex = __expf(v[j][e] - m); v[j][e] = ex; sum += ex; }
#pragma unroll
  for (int o = 32; o > 0; o >>= 1) sum += __shfl_xor(sum, o);
  __syncthreads();
  if (lane == 0) red[wave] = sum;
  __syncthreads();
  sum = red[0] + red[1] + red[2] + red[3];
  const float scale = 1.25f / sum;

#pragma unroll
  for (int j = 0; j < 4; ++j) {
    f32x4 uu = *(const f32x4*)(u + (size_t)(j * 256 + tid) * 4);
    f16x4 out;
#pragma unroll
    for (int e = 0; e < 4; ++e)
      out[e] = (f16)((uu[e] >= 0.2f) ? v[j][e] * scale : 0.0f);
    *(f16x4*)(p + (size_t)(j * 256 + tid) * 4) = out;
  }
}

// ---------------- launcher ----------------
extern "C" void kernel_launch(void* const* d_in, const int* in_sizes, int n_in,
                              void* d_out, int out_size, void* d_ws, size_t ws_size,
                              hipStream_t stream) {
  if (ws_size < WS_NEEDED) return;

  const float* x  = (const float*)d_in[0];
  const float* Wq = (const float*)d_in[1];
  const float* bq = (const float*)d_in[2];
  const float* Wk = (const float*)d_in[3];
  const float* bk = (const float*)d_in[4];
  const float* Wv = (const float*)d_in[5];
  const float* bv = (const float*)d_in[6];
  const float* du = (const float*)d_in[7];

  char* ws = (char*)d_ws;
  f16*   Vt  = (f16*)(ws + O_VT);
  f16*   Pb  = (f16*)(ws + O_ATTN);
  f16*   Q   = (f16*)(ws + O_Q);
  f16*   K   = (f16*)(ws + O_K);
  float* Sf  = (float*)(ws + O_S);
  f16*   xh  = (f16*)(ws + O_XH);
  f16*   xl  = (f16*)(ws + O_XL);
  f16*   wqh = (f16*)(ws + O_WQH);
  f16*   wql = (f16*)(ws + O_WQL);
  f16*   wkh = (f16*)(ws + O_WKH);
  f16*   wkl = (f16*)(ws + O_WKL);
  f16*   wvh = (f16*)(ws + O_WVH);
  float* out = (float*)d_out;

  hipFuncSetAttribute((const void*)gemm256_scores,
                      hipFuncAttributeMaxDynamicSharedMemorySize, 131072);
  hipFuncSetAttribute((const void*)gemm256_projqk,
                      hipFuncAttributeMaxDynamicSharedMemorySize, 131072);
  hipFuncSetAttribute((const void*)gemm_vt128,
                      hipFuncAttributeMaxDynamicSharedMemorySize, 98304);
  hipFuncSetAttribute((const void*)gemm_pv128,
                      hipFuncAttributeMaxDynamicSharedMemorySize, 98304);

  // 1) splits (one dispatch)
  split_all<<<2304, 256, 0, stream>>>(x, Wq, Wk, Wv, xh, xl, wqh, wql, wkh, wkl, wvh);

  // 2) Q+K projections, 3-pass fp16 split (256 blocks)
  gemm256_projqk<<<dim3(8, MROWS / 256), 512, 131072, stream>>>(
      xh, xl, wqh, wql, wkh, wkl, bq, bk, Q, K);

  // 3) Vt = Wv . x^T + bv (256 blocks)
  gemm_vt128<<<dim3(MROWS / 128, DD / 256), 512, 98304, stream>>>(wvh, xh, bv, Vt);

  // 4) scores = Q K^T, single-pass fp16 (K'=1024)
  gemm256_scores<<<dim3(SS / 256, SS / 256, BB), 512, 131072, stream>>>(Q, K, Sf);

  // 5) softmax + dropout -> attn fp16
  softmax_dropout<<<MROWS, 256, 0, stream>>>(Sf, du, Pb);

  // 6) out = attn @ V (256 blocks)
  gemm_pv128<<<dim3(DD / 128, SS / 256, BB), 512, 98304, stream>>>(Pb, Vt, out);
}

// Round 8
// 323.609 us; speedup vs baseline: 1.8558x; 1.1330x over previous
//
#include <hip/hip_runtime.h>

typedef float    f32x4 __attribute__((ext_vector_type(4)));
typedef _Float16 f16x8 __attribute__((ext_vector_type(8)));
typedef _Float16 f16x4 __attribute__((ext_vector_type(4)));
typedef _Float16 f16;

#define DEVFN static __device__ __forceinline__

constexpr int BB = 2, SS = 4096, DD = 1024;
constexpr int MROWS = BB * SS; // 8192

// ---------------- workspace layout (bytes) ----------------
constexpr size_t SZ_QK   = (size_t)MROWS * DD * 2;
constexpr size_t SZ_VT   = (size_t)BB * DD * SS * 2;
constexpr size_t SZ_ATTN = (size_t)BB * SS * SS * 2;
constexpr size_t SZ_S    = (size_t)BB * SS * SS * 4;
constexpr size_t SZ_W    = (size_t)DD * DD * 2;

constexpr size_t O_VT   = 0;
constexpr size_t O_ATTN = O_VT + SZ_VT;
constexpr size_t O_Q    = O_ATTN;            // Q fp16, dead after scores
constexpr size_t O_K    = O_Q + 2 * SZ_QK;   // K fp16, dead after scores
constexpr size_t O_S    = O_ATTN + SZ_ATTN;  // f32 scores
constexpr size_t O_XH   = O_S;               // phase-1 aliases in scores region
constexpr size_t O_WQH  = O_XH + SZ_QK;
constexpr size_t O_WKH  = O_WQH + SZ_W;
constexpr size_t O_WVH  = O_WKH + SZ_W;
constexpr size_t WS_NEEDED = SZ_VT + SZ_ATTN + SZ_S;

// ---------------- helpers ----------------
DEVFN f32x4 mfma16x16x32(f16x8 a, f16x8 b, f32x4 c) {
  return __builtin_amdgcn_mfma_f32_16x16x32_f16(a, b, c, 0, 0, 0);
}

DEVFN void gld16(const f16* g, char* l) {
  __builtin_amdgcn_global_load_lds((const __attribute__((address_space(1))) void*)g,
                                   (__attribute__((address_space(3))) void*)l, 16, 0, 0);
}

// bijective XCD-chunked block swizzle (requires total blocks % 8 == 0)
DEVFN void swz_xy(int& bx, int& by, int& bz) {
  const int gx = gridDim.x, gy = gridDim.y, gz = gridDim.z;
  const int lin = (blockIdx.z * gy + blockIdx.y) * gx + blockIdx.x;
  const int chunk = (gx * gy * gz) >> 3;
  const int nl = (lin & 7) * chunk + (lin >> 3);
  bx = nl % gx; const int r = nl / gx; by = r % gy; bz = r / gy;
}

// =====================================================================
// 256x256 8-phase GEMM core (counted vmcnt, never drain-0).
// Reads:  ph0: b1(cur) | ph1: a1(cur) | ph2: b0'(nxt) | ph3: a0'(nxt)
// MFMA:   ph0: a0*b0   | ph1: a0*b1   | ph2: a1*b0    | ph3: a1*b1
// Stages: ph0: A(u+1)q0,q2 | ph1: A(u+1)q1,q3 | ph2: B(u+2)q0,q1 | ph3: B(u+2)q2,q3
// =====================================================================
struct Segs { const f16 *a0, *b0; };

DEVFN void gemm256_core(Segs s, int NT, char* smem, f32x4 (&acc)[8][4]) {
  const int tid = threadIdx.x, lane = tid & 63, wave = tid >> 6;
  const int wm = wave >> 2, wn = wave & 3;
  const size_t rk = (size_t)((wave << 3) + (lane >> 3)) * DD +
                    (size_t)((((lane & 7) ^ (lane >> 3)) << 3));
  const int wvoff = wave << 10;
  const int rbA = (((wm << 7) + (lane & 15)) << 7);
  const int rbB = (((wn << 6) + (lane & 15)) << 7);
  const int cx0 = (((lane >> 4) << 4)) ^ ((lane & 7) << 4);
  const int cx1 = cx0 ^ 64;

  char* LA0 = smem;
  char* LB0 = smem + 32768;
  char* LA1 = smem + 65536;
  char* LB1 = smem + 98304;

  auto stA = [&](int u, int q, char* dst) {
    int uc = (u < NT) ? u : (NT - 1);
    gld16(s.a0 + ((size_t)(q << 6)) * DD + ((size_t)uc << 6) + rk, dst + (q << 13) + wvoff);
  };
  auto stB = [&](int u, int q, char* dst) {
    int uc = (u < NT) ? u : (NT - 1);
    gld16(s.b0 + ((size_t)(q << 6)) * DD + ((size_t)uc << 6) + rk, dst + (q << 13) + wvoff);
  };
  auto rdA = [&](char* l, int m, int cx) { return *(const f16x8*)(l + rbA + (m << 11) + cx); };
  auto rdB = [&](char* l, int n, int cx) { return *(const f16x8*)(l + rbB + (n << 11) + cx); };

  f16x8 A0[4][2], B0[2][2], A0n[4][2], B0n[2][2];

  stB(0, 0, LB0); stB(0, 1, LB0);
  stB(0, 2, LB0); stB(0, 3, LB0);
  stA(0, 0, LA0); stA(0, 2, LA0);
  stA(0, 1, LA0); stA(0, 3, LA0);
  stB(1, 0, LB1); stB(1, 1, LB1);
  stB(1, 2, LB1); stB(1, 3, LB1);
  asm volatile("s_waitcnt vmcnt(6)" ::: "memory");
  __builtin_amdgcn_s_barrier();
#pragma unroll
  for (int n = 0; n < 2; ++n) { B0[n][0] = rdB(LB0, n, cx0); B0[n][1] = rdB(LB0, n, cx1); }
#pragma unroll
  for (int m = 0; m < 4; ++m) { A0[m][0] = rdA(LA0, m, cx0); A0[m][1] = rdA(LA0, m, cx1); }

  auto tile = [&](char* lA, char* lB, char* lAn, char* lBn, int t,
                  f16x8 (&a0)[4][2], f16x8 (&b0)[2][2],
                  f16x8 (&a0n)[4][2], f16x8 (&b0n)[2][2]) {
    f16x8 a1[4][2], b1[2][2];
    // ph0
#pragma unroll
    for (int n = 0; n < 2; ++n) { b1[n][0] = rdB(lB, n + 2, cx0); b1[n][1] = rdB(lB, n + 2, cx1); }
    stA(t + 1, 0, lAn); stA(t + 1, 2, lAn);
    asm volatile("s_waitcnt vmcnt(4)" ::: "memory");
    __builtin_amdgcn_s_barrier();
    asm volatile("s_waitcnt lgkmcnt(4)" ::: "memory");
    __builtin_amdgcn_sched_barrier(0);
    __builtin_amdgcn_s_setprio(1);
#pragma unroll
    for (int m = 0; m < 4; ++m)
#pragma unroll
      for (int n = 0; n < 2; ++n) {
        acc[m][n] = mfma16x16x32(a0[m][0], b0[n][0], acc[m][n]);
        acc[m][n] = mfma16x16x32(a0[m][1], b0[n][1], acc[m][n]);
      }
    __builtin_amdgcn_s_setprio(0);
    __builtin_amdgcn_s_barrier();
    // ph1
#pragma unroll
    for (int m = 0; m < 4; ++m) { a1[m][0] = rdA(lA, m + 4, cx0); a1[m][1] = rdA(lA, m + 4, cx1); }
    stA(t + 1, 1, lAn); stA(t + 1, 3, lAn);
    asm volatile("s_waitcnt vmcnt(4)" ::: "memory");
    __builtin_amdgcn_s_barrier();
    asm volatile("s_waitcnt lgkmcnt(8)" ::: "memory");
    __builtin_amdgcn_sched_barrier(0);
    __builtin_amdgcn_s_setprio(1);
#pragma unroll
    for (int m = 0; m < 4; ++m)
#pragma unroll
      for (int n = 0; n < 2; ++n) {
        acc[m][n + 2] = mfma16x16x32(a0[m][0], b1[n][0], acc[m][n + 2]);
        acc[m][n + 2] = mfma16x16x32(a0[m][1], b1[n][1], acc[m][n + 2]);
      }
    __builtin_amdgcn_s_setprio(0);
    __builtin_amdgcn_s_barrier();
    // ph2
#pragma unroll
    for (int n = 0; n < 2; ++n) { b0n[n][0] = rdB(lBn, n, cx0); b0n[n][1] = rdB(lBn, n, cx1); }
    stB(t + 2, 0, lB); stB(t + 2, 1, lB);
    asm volatile("s_waitcnt vmcnt(4)" ::: "memory");
    __builtin_amdgcn_s_barrier();
    asm volatile("s_waitcnt lgkmcnt(4)" ::: "memory");
    __builtin_amdgcn_sched_barrier(0);
    __builtin_amdgcn_s_setprio(1);
#pragma unroll
    for (int m = 0; m < 4; ++m)
#pragma unroll
      for (int n = 0; n < 2; ++n) {
        acc[m + 4][n] = mfma16x16x32(a1[m][0], b0[n][0], acc[m + 4][n]);
        acc[m + 4][n] = mfma16x16x32(a1[m][1], b0[n][1], acc[m + 4][n]);
      }
    __builtin_amdgcn_s_setprio(0);
    __builtin_amdgcn_s_barrier();
    // ph3
#pragma unroll
    for (int m = 0; m < 4; ++m) { a0n[m][0] = rdA(lAn, m, cx0); a0n[m][1] = rdA(lAn, m, cx1); }
    stB(t + 2, 2, lB); stB(t + 2, 3, lB);
    asm volatile("s_waitcnt vmcnt(4)" ::: "memory");
    __builtin_amdgcn_s_barrier();
    asm volatile("s_waitcnt lgkmcnt(8)" ::: "memory");
    __builtin_amdgcn_sched_barrier(0);
    __builtin_amdgcn_s_setprio(1);
#pragma unroll
    for (int m = 0; m < 4; ++m)
#pragma unroll
      for (int n = 0; n < 2; ++n) {
        acc[m + 4][n + 2] = mfma16x16x32(a1[m][0], b1[n][0], acc[m + 4][n + 2]);
        acc[m + 4][n + 2] = mfma16x16x32(a1[m][1], b1[n][1], acc[m + 4][n + 2]);
      }
    __builtin_amdgcn_s_setprio(0);
    __builtin_amdgcn_s_barrier();
  };

  for (int t = 0; t < NT; t += 2) {
    tile(LA0, LB0, LA1, LB1, t,     A0,  B0,  A0n, B0n);
    tile(LA1, LB1, LA0, LB0, t + 1, A0n, B0n, A0,  B0);
  }
  asm volatile("s_waitcnt vmcnt(0)" ::: "memory");
}

// =====================================================================
// 256x128 8-phase GEMM core (fp16)
// =====================================================================
DEVFN void gemm128_core(const f16* Ap, const f16* Bp, size_t ld, int NT,
                        char* smem, f32x4 (&acc)[4][4]) {
  const int tid = threadIdx.x, lane = tid & 63, wave = tid >> 6;
  const int wm = wave >> 1, wn = wave & 1;
  const size_t rk = (size_t)(tid >> 3) * ld +
                    (size_t)((((lane & 7) ^ (lane >> 3)) << 3));
  const int wvoff = wave << 10;
  const int rbA = (((wm << 6) + (lane & 15)) << 7);
  const int rbB = (((wn << 6) + (lane & 15)) << 7);
  const int cx0 = (((lane >> 4) << 4)) ^ ((lane & 7) << 4);
  const int cx1 = cx0 ^ 64;

  char* LA0 = smem;
  char* LB0 = smem + 32768;
  char* LA1 = smem + 49152;
  char* LB1 = smem + 81920;

  auto stA = [&](int u, int q, char* dst) {
    int uc = (u < NT) ? u : (NT - 1);
    gld16(Ap + (size_t)(q << 6) * ld + ((size_t)uc << 6) + rk, dst + (q << 13) + wvoff);
  };
  auto stB = [&](int u, int q, char* dst) {
    int uc = (u < NT) ? u : (NT - 1);
    gld16(Bp + (size_t)(q << 6) * ld + ((size_t)uc << 6) + rk, dst + (q << 13) + wvoff);
  };
  auto rdA = [&](char* l, int m, int cx) { return *(const f16x8*)(l + rbA + (m << 11) + cx); };
  auto rdB = [&](char* l, int n, int cx) { return *(const f16x8*)(l + rbB + (n << 11) + cx); };

  f16x8 A0[2][2], B0[2][2], A0n[2][2], B0n[2][2];

  stA(0, 0, LA0); stA(0, 1, LA0); stA(0, 2, LA0); stA(0, 3, LA0);
  stB(0, 0, LB0); stB(0, 1, LB0);
  stB(1, 0, LB1); stB(1, 1, LB1);
  asm volatile("s_waitcnt vmcnt(2)" ::: "memory");
  __builtin_amdgcn_s_barrier();
#pragma unroll
  for (int n = 0; n < 2; ++n) { B0[n][0] = rdB(LB0, n, cx0); B0[n][1] = rdB(LB0, n, cx1); }
#pragma unroll
  for (int m = 0; m < 2; ++m) { A0[m][0] = rdA(LA0, m, cx0); A0[m][1] = rdA(LA0, m, cx1); }

  auto tile = [&](char* lA, char* lB, char* lAn, char* lBn, int t,
                  f16x8 (&a0)[2][2], f16x8 (&b0)[2][2],
                  f16x8 (&a0n)[2][2], f16x8 (&b0n)[2][2]) {
    f16x8 a1[2][2], b1[2][2];
    // ph0
#pragma unroll
    for (int n = 0; n < 2; ++n) { b1[n][0] = rdB(lB, n + 2, cx0); b1[n][1] = rdB(lB, n + 2, cx1); }
    stA(t + 1, 0, lAn); stA(t + 1, 1, lAn);
    __builtin_amdgcn_s_barrier();
    asm volatile("s_waitcnt lgkmcnt(4)" ::: "memory");
    __builtin_amdgcn_sched_barrier(0);
    __builtin_amdgcn_s_setprio(1);
#pragma unroll
    for (int m = 0; m < 2; ++m)
#pragma unroll
      for (int n = 0; n < 2; ++n) {
        acc[m][n] = mfma16x16x32(a0[m][0], b0[n][0], acc[m][n]);
        acc[m][n] = mfma16x16x32(a0[m][1], b0[n][1], acc[m][n]);
      }
    __builtin_amdgcn_s_setprio(0);
    __builtin_amdgcn_s_barrier();
    // ph1
#pragma unroll
    for (int m = 0; m < 2; ++m) { a1[m][0] = rdA(lA, m + 2, cx0); a1[m][1] = rdA(lA, m + 2, cx1); }
    stA(t + 1, 2, lAn); stA(t + 1, 3, lAn);
    asm volatile("s_waitcnt vmcnt(4)" ::: "memory");
    __builtin_amdgcn_s_barrier();
    asm volatile("s_waitcnt lgkmcnt(4)" ::: "memory");
    __builtin_amdgcn_sched_barrier(0);
    __builtin_amdgcn_s_setprio(1);
#pragma unroll
    for (int m = 0; m < 2; ++m)
#pragma unroll
      for (int n = 0; n < 2; ++n) {
        acc[m][n + 2] = mfma16x16x32(a0[m][0], b1[n][0], acc[m][n + 2]);
        acc[m][n + 2] = mfma16x16x32(a0[m][1], b1[n][1], acc[m][n + 2]);
      }
    __builtin_amdgcn_s_setprio(0);
    __builtin_amdgcn_s_barrier();
    // ph2
#pragma unroll
    for (int n = 0; n < 2; ++n) { b0n[n][0] = rdB(lBn, n, cx0); b0n[n][1] = rdB(lBn, n, cx1); }
    stB(t + 2, 0, lB); stB(t + 2, 1, lB);
    asm volatile("s_waitcnt vmcnt(2)" ::: "memory");
    __builtin_amdgcn_s_barrier();
    asm volatile("s_waitcnt lgkmcnt(4)" ::: "memory");
    __builtin_amdgcn_sched_barrier(0);
    __builtin_amdgcn_s_setprio(1);
#pragma unroll
    for (int m = 0; m < 2; ++m)
#pragma unroll
      for (int n = 0; n < 2; ++n) {
        acc[m + 2][n] = mfma16x16x32(a1[m][0], b0[n][0], acc[m + 2][n]);
        acc[m + 2][n] = mfma16x16x32(a1[m][1], b0[n][1], acc[m + 2][n]);
      }
    __builtin_amdgcn_s_setprio(0);
    __builtin_amdgcn_s_barrier();
    // ph3
#pragma unroll
    for (int m = 0; m < 2; ++m) { a0n[m][0] = rdA(lAn, m, cx0); a0n[m][1] = rdA(lAn, m, cx1); }
    __builtin_amdgcn_s_barrier();
    asm volatile("s_waitcnt lgkmcnt(4)" ::: "memory");
    __builtin_amdgcn_sched_barrier(0);
    __builtin_amdgcn_s_setprio(1);
#pragma unroll
    for (int m = 0; m < 2; ++m)
#pragma unroll
      for (int n = 0; n < 2; ++n) {
        acc[m + 2][n + 2] = mfma16x16x32(a1[m][0], b1[n][0], acc[m + 2][n + 2]);
        acc[m + 2][n + 2] = mfma16x16x32(a1[m][1], b1[n][1], acc[m + 2][n + 2]);
      }
    __builtin_amdgcn_s_setprio(0);
    __builtin_amdgcn_s_barrier();
  };

  for (int t = 0; t < NT; t += 2) {
    tile(LA0, LB0, LA1, LB1, t,     A0, B0, A0n, B0n);
    tile(LA1, LB1, LA0, LB0, t + 1, A0n, B0n, A0, B0);
  }
  asm volatile("s_waitcnt vmcnt(0)" ::: "memory");
}

// ---------------- scores = Q . K^T (single-pass fp16, fp32 out) ----------------
__global__ __launch_bounds__(512, 2)
void gemm256_scores(const f16* __restrict__ Q, const f16* __restrict__ K,
                    float* __restrict__ Sf) {
  extern __shared__ char smem[];
  int bx, by, bz; swz_xy(bx, by, bz);
  const size_t zo = (size_t)bz * SS * DD;
  const int row0 = by * 256, col0 = bx * 256;
  Segs s{Q + zo + (size_t)row0 * DD, K + zo + (size_t)col0 * DD};
  f32x4 acc[8][4] = {};
  gemm256_core(s, 16, smem, acc);

  float* C = Sf + (size_t)bz * SS * SS;
  const int lane = threadIdx.x & 63, wave = threadIdx.x >> 6;
  const int wm = wave >> 2, wn = wave & 3;
#pragma unroll
  for (int m = 0; m < 8; ++m)
#pragma unroll
    for (int n = 0; n < 4; ++n) {
      int col = col0 + wn * 64 + n * 16 + (lane & 15);
      int rowb = row0 + wm * 128 + m * 16 + (lane >> 4) * 4;
#pragma unroll
      for (int j = 0; j < 4; ++j)
        C[(size_t)(rowb + j) * SS + col] = acc[m][n][j];
    }
}

// ---------------- fused Q+K projections, single-pass fp16 -------
__global__ __launch_bounds__(512, 2)
void gemm256_projqk(const f16* __restrict__ xh,
                    const f16* __restrict__ wqh, const f16* __restrict__ wkh,
                    const float* __restrict__ bq, const float* __restrict__ bk,
                    f16* __restrict__ Q, f16* __restrict__ K) {
  extern __shared__ char smem[];
  int bx, by, bz; swz_xy(bx, by, bz);
  const int row0 = by * 256;
  const int cg = bx;                  // 0..3 = Q cols, 4..7 = K cols
  const bool isK = cg >= 4;
  const int col0 = (cg & 3) * 256;
  const f16* B0p = isK ? wkh : wqh;
  const float* bias = isK ? bk : bq;
  f16* CH = isK ? K : Q;

  Segs s{xh + (size_t)row0 * DD, B0p + (size_t)col0 * DD};
  f32x4 acc[8][4] = {};
  gemm256_core(s, 16, smem, acc);

  const int lane = threadIdx.x & 63, wave = threadIdx.x >> 6;
  const int wm = wave >> 2, wn = wave & 3;
#pragma unroll
  for (int m = 0; m < 8; ++m)
#pragma unroll
    for (int n = 0; n < 4; ++n) {
      int col = col0 + wn * 64 + n * 16 + (lane & 15);
      float bvv = bias[col];
      int rowb = row0 + wm * 128 + m * 16 + (lane >> 4) * 4;
#pragma unroll
      for (int j = 0; j < 4; ++j)
        CH[(size_t)(rowb + j) * DD + col] = (f16)(acc[m][n][j] + bvv);
    }
}

// ---------------- Vt = Wv . x^T (256x128 core, 256 blocks) ----------------
__global__ __launch_bounds__(512, 2)
void gemm_vt128(const f16* __restrict__ wvh, const f16* __restrict__ xh,
                const float* __restrict__ bvv, f16* __restrict__ Vt) {
  extern __shared__ char smem[];
  int bx, by, bz; swz_xy(bx, by, bz);
  const int row0 = by * 256;  // d
  const int col0 = bx * 128;  // s global (0..8191)
  f32x4 acc[4][4] = {};
  gemm128_core(wvh + (size_t)row0 * DD, xh + (size_t)col0 * DD, DD, 16, smem, acc);

  const int lane = threadIdx.x & 63, wave = threadIdx.x >> 6;
  const int wm = wave >> 1, wn = wave & 1;
#pragma unroll
  for (int m = 0; m < 4; ++m)
#pragma unroll
    for (int n = 0; n < 4; ++n) {
      int col = col0 + wn * 64 + n * 16 + (lane & 15);
      int batch = col >> 12, sl = col & 4095;
      int rowb = row0 + wm * 64 + m * 16 + (lane >> 4) * 4;
#pragma unroll
      for (int j = 0; j < 4; ++j) {
        float v = acc[m][n][j] + bvv[rowb + j];
        Vt[(size_t)batch * DD * SS + (size_t)(rowb + j) * SS + sl] = (f16)v;
      }
    }
}

// ---------------- out = attn @ V (256x128 core, 256 blocks) ----------------
__global__ __launch_bounds__(512, 2)
void gemm_pv128(const f16* __restrict__ Pb, const f16* __restrict__ Vt,
                float* __restrict__ out) {
  extern __shared__ char smem[];
  int bx, by, bz; swz_xy(bx, by, bz);
  const int row0 = by * 256;  // q
  const int col0 = bx * 128;  // d
  f32x4 acc[4][4] = {};
  gemm128_core(Pb + (size_t)bz * SS * SS + (size_t)row0 * SS,
               Vt + (size_t)bz * DD * SS + (size_t)col0 * SS,
               SS, 64, smem, acc);

  float* C = out + (size_t)bz * SS * DD;
  const int lane = threadIdx.x & 63, wave = threadIdx.x >> 6;
  const int wm = wave >> 1, wn = wave & 1;
#pragma unroll
  for (int m = 0; m < 4; ++m)
#pragma unroll
    for (int n = 0; n < 4; ++n) {
      int col = col0 + wn * 64 + n * 16 + (lane & 15);
      int rowb = row0 + wm * 64 + m * 16 + (lane >> 4) * 4;
#pragma unroll
      for (int j = 0; j < 4; ++j)
        C[(size_t)(rowb + j) * DD + col] = acc[m][n][j];
    }
}

// ---------------- fused casts: x, Wq, Wk, Wv -> fp16 in one dispatch ------------
__global__ __launch_bounds__(256)
void split_all(const float* __restrict__ x, const float* __restrict__ Wq,
               const float* __restrict__ Wk, const float* __restrict__ Wv,
               f16* __restrict__ xh, f16* __restrict__ wqh,
               f16* __restrict__ wkh, f16* __restrict__ wvh) {
  const int b = blockIdx.x, tid = threadIdx.x;
  const float* in; f16* hi; int nv, rb, nb;
  if (b < 1536)      { in = x;  hi = xh;  nv = (MROWS * DD) >> 2; rb = b;        nb = 1536; }
  else if (b < 1792) { in = Wq; hi = wqh; nv = (DD * DD) >> 2;    rb = b - 1536; nb = 256; }
  else if (b < 2048) { in = Wk; hi = wkh; nv = (DD * DD) >> 2;    rb = b - 1792; nb = 256; }
  else               { in = Wv; hi = wvh; nv = (DD * DD) >> 2;    rb = b - 2048; nb = 256; }
  for (int i = rb * 256 + tid; i < nv; i += nb * 256) {
    f32x4 v = *(const f32x4*)(in + (size_t)i * 4);
    f16x4 h;
#pragma unroll
    for (int e = 0; e < 4; ++e) h[e] = (f16)v[e];
    *(f16x4*)(hi + (size_t)i * 4) = h;
  }
}

// ---------------- softmax + dropout (fp16 out) ----------------
__global__ __launch_bounds__(256)
void softmax_dropout(const float* __restrict__ Sf, const float* __restrict__ U,
                     f16* __restrict__ P) {
  __shared__ float red[4];
  const size_t row = blockIdx.x;
  const float* s = Sf + row * SS;
  const float* u = U + row * SS;
  f16* p = P + row * SS;
  const int tid = threadIdx.x, lane = tid & 63, wave = tid >> 6;

  f32x4 v[4];
  float m = -3.0e38f;
#pragma unroll
  for (int j = 0; j < 4; ++j) {
    v[j] = *(const f32x4*)(s + (size_t)(j * 256 + tid) * 4);
#pragma unroll
    for (int e = 0; e < 4; ++e) m = fmaxf(m, v[j][e]);
  }
#pragma unroll
  for (int o = 32; o > 0; o >>= 1) m = fmaxf(m, __shfl_xor(m, o));
  if (lane == 0) red[wave] = m;
  __syncthreads();
  m = fmaxf(fmaxf(red[0], red[1]), fmaxf(red[2], red[3]));

  float sum = 0.0f;
#pragma unroll
  for (int j = 0; j < 4; ++j)
#pragma unroll
    for (int e = 0; e < 4; ++e) { float ex = __expf(v[j][e] - m); v[j][e] = ex; sum += ex; }
#pragma unroll
  for (int o = 32; o > 0; o >>= 1) sum += __shfl_xor(sum, o);
  __syncthreads();
  if (lane == 0) red[wave] = sum;
  __syncthreads();
  sum = red[0] + red[1] + red[2] + red[3];
  const float scale = 1.25f / sum;

#pragma unroll
  for (int j = 0; j < 4; ++j) {
    f32x4 uu = *(const f32x4*)(u + (size_t)(j * 256 + tid) * 4);
    f16x4 out;
#pragma unroll
    for (int e = 0; e < 4; ++e)
      out[e] = (f16)((uu[e] >= 0.2f) ? v[j][e] * scale : 0.0f);
    *(f16x4*)(p + (size_t)(j * 256 + tid) * 4) = out;
  }
}

// ---------------- launcher ----------------
extern "C" void kernel_launch(void* const* d_in, const int* in_sizes, int n_in,
                              void* d_out, int out_size, void* d_ws, size_t ws_size,
                              hipStream_t stream) {
  if (ws_size < WS_NEEDED) return;

  const float* x  = (const float*)d_in[0];
  const float* Wq = (const float*)d_in[1];
  const float* bq = (const float*)d_in[2];
  const float* Wk = (const float*)d_in[3];
  const float* bk = (const float*)d_in[4];
  const float* Wv = (const float*)d_in[5];
  const float* bv = (const float*)d_in[6];
  const float* du = (const float*)d_in[7];

  char* ws = (char*)d_ws;
  f16*   Vt  = (f16*)(ws + O_VT);
  f16*   Pb  = (f16*)(ws + O_ATTN);
  f16*   Q   = (f16*)(ws + O_Q);
  f16*   K   = (f16*)(ws + O_K);
  float* Sf  = (float*)(ws + O_S);
  f16*   xh  = (f16*)(ws + O_XH);
  f16*   wqh = (f16*)(ws + O_WQH);
  f16*   wkh = (f16*)(ws + O_WKH);
  f16*   wvh = (f16*)(ws + O_WVH);
  float* out = (float*)d_out;

  hipFuncSetAttribute((const void*)gemm256_scores,
                      hipFuncAttributeMaxDynamicSharedMemorySize, 131072);
  hipFuncSetAttribute((const void*)gemm256_projqk,
                      hipFuncAttributeMaxDynamicSharedMemorySize, 131072);
  hipFuncSetAttribute((const void*)gemm_vt128,
                      hipFuncAttributeMaxDynamicSharedMemorySize, 98304);
  hipFuncSetAttribute((const void*)gemm_pv128,
                      hipFuncAttributeMaxDynamicSharedMemorySize, 98304);

  // 1) casts (one dispatch)
  split_all<<<2304, 256, 0, stream>>>(x, Wq, Wk, Wv, xh, wqh, wkh, wvh);

  // 2) Q+K projections, single-pass fp16 (256 blocks, NT=16)
  gemm256_projqk<<<dim3(8, MROWS / 256), 512, 131072, stream>>>(
      xh, wqh, wkh, bq, bk, Q, K);

  // 3) Vt = Wv . x^T + bv (256 blocks)
  gemm_vt128<<<dim3(MROWS / 128, DD / 256), 512, 98304, stream>>>(wvh, xh, bv, Vt);

  // 4) scores = Q K^T, single-pass fp16 (K'=1024)
  gemm256_scores<<<dim3(SS / 256, SS / 256, BB), 512, 131072, stream>>>(Q, K, Sf);

  // 5) softmax + dropout -> attn fp16
  softmax_dropout<<<MROWS, 256, 0, stream>>>(Sf, du, Pb);

  // 6) out = attn @ V (256 blocks)
  gemm_pv128<<<dim3(DD / 128, SS / 256, BB), 512, 98304, stream>>>(Pb, Vt, out);
}